// Round 4
// baseline (1674.146 us; speedup 1.0000x reference)
//
#include <hip/hip_runtime.h>
#include <hip/hip_bf16.h>
#include <math.h>

#define B_ 128
#define L_ 196
#define D_ 512
#define T_ 20
#define V_ 10000
#define E_ 256
#define H_ 512
#define A_ 512
#define TM1 19
#define ROWS (TM1*B_)      /* 2432 */
#define G4H 2048
#define KCAT 1024
#define NBLK 128

typedef unsigned short ushort_t;
typedef __attribute__((ext_vector_type(8))) short bf16x8;
typedef __attribute__((ext_vector_type(4))) float f32x4;

__device__ __forceinline__ float fast_tanh(float x){
    float ax = fabsf(x);
    float e = __expf(-2.f*ax);
    float r = __builtin_amdgcn_rcpf(1.f + e);
    return copysignf((1.f - e)*r, x);
}
__device__ __forceinline__ float sigmoidf_(float x){
    return __builtin_amdgcn_rcpf(1.f + __expf(-x));
}
__device__ __forceinline__ ushort_t f2b(float f){
    union{float f; unsigned u;} x; x.f = f;
    unsigned r = x.u + 0x7fffu + ((x.u>>16)&1u);
    return (ushort_t)(r>>16);
}
__device__ __forceinline__ float b2f(ushort_t h){
    union{unsigned u; float f;} x; x.u = ((unsigned)h)<<16;
    return x.f;
}
__device__ __forceinline__ float b2f_lo(unsigned u){ union{unsigned u; float f;} x; x.u = u<<16; return x.f; }
__device__ __forceinline__ float b2f_hi(unsigned u){ union{unsigned u; float f;} x; x.u = u & 0xffff0000u; return x.f; }

// ================= bf16 MFMA GEMM: C = A @ BT^T (+bias) =================
// SWZ=1: logits shape only (79 n-tiles padded to 80, 19 m-tiles), XCD-contiguous n-slices
template<int OUT_BF16, int HAS_BIAS, int NT, int SWZ>
__global__ __launch_bounds__(256)
void gemm_mfma(const ushort_t* __restrict__ A, int lda,
               const ushort_t* __restrict__ BT, int ldb,
               void* __restrict__ Cout, int ldc,
               int N, int K, const float* __restrict__ bias)
{
    __shared__ ushort_t As[128*32];
    __shared__ ushort_t Bs[128*32];
    int bm, bn;
    if (SWZ){
        int bid = blockIdx.x;                 // 0..1519
        int swz = (bid & 7)*190 + (bid >> 3); // XCD-contiguous chunks
        int mt = swz % 19, nt = swz / 19;     // nt 0..79
        if (nt >= 79) return;
        bm = mt*128; bn = nt*128;
    } else {
        bm = blockIdx.y * 128; bn = blockIdx.x * 128;
    }
    const int tid = threadIdx.x;
    const int lane = tid & 63;
    const int wave = tid >> 6;
    const int wm = (wave >> 1) * 64;
    const int wn = (wave & 1) * 64;
    const int lrow = lane & 15;
    const int lk8  = (lane >> 4) * 8;
    const int srow = tid >> 2;
    const int skq  = (tid & 3) * 8;

    f32x4 acc[4][4];
    #pragma unroll
    for (int i=0;i<4;i++)
        #pragma unroll
        for (int j=0;j<4;j++) acc[i][j] = (f32x4){0.f,0.f,0.f,0.f};

    const ushort_t* Abase = A  + (size_t)(bm+srow)*lda + skq;
    const ushort_t* Bbase = BT + (size_t)(bn+srow)*ldb + skq;

    for (int k0 = 0; k0 < K; k0 += 32) {
        int4 a0 = *(const int4*)(Abase + k0);
        int4 a1 = *(const int4*)(Abase + (size_t)64*lda + k0);
        int4 b0 = *(const int4*)(Bbase + k0);
        int4 b1 = *(const int4*)(Bbase + (size_t)64*ldb + k0);
        __syncthreads();
        *(int4*)&As[srow*32 + skq]      = a0;
        *(int4*)&As[(srow+64)*32 + skq] = a1;
        *(int4*)&Bs[srow*32 + skq]      = b0;
        *(int4*)&Bs[(srow+64)*32 + skq] = b1;
        __syncthreads();
        bf16x8 af[4], bfr[4];
        #pragma unroll
        for (int i=0;i<4;i++) af[i]  = *(bf16x8*)&As[(wm + i*16 + lrow)*32 + lk8];
        #pragma unroll
        for (int j=0;j<4;j++) bfr[j] = *(bf16x8*)&Bs[(wn + j*16 + lrow)*32 + lk8];
        #pragma unroll
        for (int i=0;i<4;i++)
            #pragma unroll
            for (int j=0;j<4;j++)
                acc[i][j] = __builtin_amdgcn_mfma_f32_16x16x32_bf16(af[i], bfr[j], acc[i][j], 0, 0, 0);
    }

    const int rq = (lane >> 4) * 4;
    #pragma unroll
    for (int j=0;j<4;j++){
        int col = bn + wn + j*16 + lrow;
        if (col >= N) continue;
        float bv = HAS_BIAS ? bias[col] : 0.f;
        #pragma unroll
        for (int i=0;i<4;i++){
            #pragma unroll
            for (int q=0;q<4;q++){
                int row = bm + wm + i*16 + rq + q;
                float v = acc[i][j][q] + bv;
                if (OUT_BF16) ((ushort_t*)Cout)[(size_t)row*ldc + col] = f2b(v);
                else if (NT)  __builtin_nontemporal_store(v, &((float*)Cout)[(size_t)row*ldc + col]);
                else          ((float*)Cout)[(size_t)row*ldc + col] = v;
            }
        }
    }
}

// ============ f32 tile GEMM (init path): C = tanh(A@B + bias) ============
__global__ __launch_bounds__(256) void gemm64t(const float* __restrict__ A, int lda,
                       const float* __restrict__ Bm, int ldb,
                       float* __restrict__ C, int ldc, const float* __restrict__ bias)
{
    __shared__ float As[16][65];
    __shared__ float Bs[16][65];
    int bm = blockIdx.y*64, bn = blockIdx.x*64;
    int tid = threadIdx.x;
    int tx = tid & 15, ty = tid >> 4;
    float acc[4][4] = {};
    for (int k0 = 0; k0 < D_; k0 += 16) {
        {
            int r  = tid >> 2;
            int kq = (tid & 3) * 4;
            float4 va = *(const float4*)(A + (size_t)(bm+r)*lda + k0 + kq);
            As[kq+0][r]=va.x; As[kq+1][r]=va.y; As[kq+2][r]=va.z; As[kq+3][r]=va.w;
        }
        {
            int kk = tid >> 4;
            int nq = (tid & 15) * 4;
            float4 vb = *(const float4*)(Bm + (size_t)(k0+kk)*ldb + bn + nq);
            Bs[kk][nq+0]=vb.x; Bs[kk][nq+1]=vb.y; Bs[kk][nq+2]=vb.z; Bs[kk][nq+3]=vb.w;
        }
        __syncthreads();
        #pragma unroll
        for (int k = 0; k < 16; ++k) {
            float a0[4], b0[4];
            #pragma unroll
            for (int i=0;i<4;i++) a0[i] = As[k][ty*4+i];
            #pragma unroll
            for (int j=0;j<4;j++) b0[j] = Bs[k][tx*4+j];
            #pragma unroll
            for (int i=0;i<4;i++)
                #pragma unroll
                for (int j=0;j<4;j++)
                    acc[i][j] = fmaf(a0[i], b0[j], acc[i][j]);
        }
        __syncthreads();
    }
    #pragma unroll
    for (int i=0;i<4;i++){
        int row = bm + ty*4 + i;
        #pragma unroll
        for (int j=0;j<4;j++){
            int col = bn + tx*4 + j;
            C[(size_t)row*ldc + col] = fast_tanh(acc[i][j] + bias[col]);
        }
    }
}

// ================= prep kernels =================
__global__ void transpose_cvt(const float* __restrict__ src, const float* __restrict__ src2,
                              int lds_, int Ksz, int Nsz,
                              ushort_t* __restrict__ dst, int ldk, int koff)
{
    __shared__ float t[32][33];
    int n0 = blockIdx.x*32, k0 = blockIdx.y*32;
    int tx = threadIdx.x & 31, ty = threadIdx.x >> 5;
    #pragma unroll
    for (int kk = ty; kk < 32; kk += 8){
        int k = k0 + kk, n = n0 + tx;
        float v = 0.f;
        if (k < Ksz && n < Nsz){
            v = src[(size_t)k*lds_ + n];
            if (src2) v += src2[(size_t)k*lds_ + n];
        }
        t[kk][tx] = v;
    }
    __syncthreads();
    #pragma unroll
    for (int nn = ty; nn < 32; nn += 8){
        int n = n0 + nn, k = k0 + tx;
        if (k < Ksz) dst[(size_t)n*ldk + koff + k] = f2b(t[tx][nn]);
    }
}

__global__ void bias4h_k(const float* __restrict__ b_ih, const float* __restrict__ b_hh,
                         float* __restrict__ bias4h, unsigned* __restrict__ bar){
    int i = blockIdx.x*blockDim.x + threadIdx.x;
    if (i < G4H) bias4h[i] = b_ih[i] + b_hh[i];
    if (i == 0) *bar = 0u;
}

__global__ __launch_bounds__(256) void mean_cvt_k(const float* __restrict__ a, ushort_t* __restrict__ a_b,
                                                  float* __restrict__ mc){
    int idx = blockIdx.x*256 + threadIdx.x;   // b*512 + d
    int b = idx >> 9, d = idx & 511;
    const float* p = a + (size_t)b*L_*D_ + d;
    ushort_t* q = a_b + (size_t)b*L_*D_ + d;
    float s = 0.f;
    for (int l=0;l<L_;l++){ float v = p[(size_t)l*D_]; s += v; q[(size_t)l*D_] = f2b(v); }
    mc[idx] = s * (1.f/(float)L_);
}

__global__ void gather_emb(const int* __restrict__ captions, const float* __restrict__ embW,
                           ushort_t* __restrict__ xemb){
    int i = blockIdx.x;                 // t*B + b
    int t = i / B_, b = i - t*B_;
    int cap = captions[b*T_ + t];
    float4 v = ((const float4*)(embW + (size_t)cap*E_))[threadIdx.x];
    ushort_t r[4] = {f2b(v.x),f2b(v.y),f2b(v.z),f2b(v.w)};
    *(uint2*)(xemb + (size_t)i*E_ + threadIdx.x*4) = *(uint2*)r;
}

__global__ void cvt_h0_k(const float* __restrict__ h0f, ushort_t* __restrict__ xcat){
    int idx = blockIdx.x*blockDim.x + threadIdx.x;   // b*512 + j
    int b = idx >> 9, j = idx & 511;
    xcat[(size_t)b*KCAT + D_ + j] = f2b(h0f[idx]);
}

// ================= persistent cooperative loop kernel =================
struct LoopArgs {
    const ushort_t* wa_b;
    const ushort_t* a_b;
    const float* v;
    const float* beta_W;
    const float* beta_b;
    const ushort_t* WcatT;
    const ushort_t* WhcT;
    const float* embWih;
    float* cbuf;
    ushort_t* xcat;
    ushort_t* Hall;
    float* gp;
    float* alphas;
    unsigned* bar;
};

// hW = h @ Whc via MFMA (h broadcast in A row 0); result -> LDS hWl[512]
__device__ __forceinline__ void hw_mfma_lds(const ushort_t* hls, const ushort_t* __restrict__ WhcT,
                                            float* hWl, int j){
    int lane = j & 63, wave = j >> 6;
    int wn = wave * 64;
    int col16 = lane & 15;
    int khi = (lane >> 4) * 8;
    bool a_on = (col16 == 0);
    f32x4 acc[4];
    #pragma unroll
    for (int f=0;f<4;f++) acc[f] = (f32x4){0.f,0.f,0.f,0.f};
    for (int kk=0; kk<16; kk++){
        bf16x8 af = (bf16x8){0,0,0,0,0,0,0,0};
        if (a_on) af = *(const bf16x8*)&hls[kk*32 + khi];
        #pragma unroll
        for (int f=0;f<4;f++){
            bf16x8 bf = *(const bf16x8*)(WhcT + (size_t)(wn + f*16 + col16)*512 + kk*32 + khi);
            acc[f] = __builtin_amdgcn_mfma_f32_16x16x32_bf16(af, bf, acc[f], 0, 0, 0);
        }
    }
    if (lane < 16){
        #pragma unroll
        for (int f=0;f<4;f++) hWl[wn + f*16 + lane] = acc[f][0];
    }
}

__device__ __forceinline__ void grid_sync(unsigned* bar, unsigned target){
    __syncthreads();
    if (threadIdx.x == 0){
        __threadfence();
        atomicAdd(bar, 1u);
        while (__hip_atomic_load(bar, __ATOMIC_ACQUIRE, __HIP_MEMORY_SCOPE_AGENT) < target){
            __builtin_amdgcn_s_sleep(1);
        }
    }
    __syncthreads();
}

__global__ __launch_bounds__(512) void loop_k(LoopArgs p){
    const int blk = blockIdx.x;       // 0..127 == batch b for phases A/C
    const int tid = threadIdx.x;      // 0..511
    const int lane = tid & 63, wave = tid >> 6;
    __shared__ float hWl[512];
    __shared__ char smem[12288];
    unsigned tgt = 0;

    // ---- init: hW = h0 @ Whc ----
    {
        ushort_t* hls = (ushort_t*)smem;
        hls[tid] = p.xcat[(size_t)blk*KCAT + D_ + tid];
        __syncthreads();
        hw_mfma_lds(hls, p.WhcT, hWl, tid);
        __syncthreads();
    }

    for (int t = 0; t < TM1; ++t){
        // ================= phase A: e, softmax, beta, ctx (block-local in b) =================
        {
            float* e_s  = (float*)smem;
            float* al_s = e_s + 224;
            float* red_s= al_s + 224;
            float4 hw0 = *(float4*)&hWl[lane*8];
            float4 hw1 = *(float4*)&hWl[lane*8 + 4];
            const float* vp = p.v + lane*8;
            float4 v0 = *(const float4*)vp, v1 = *(const float4*)(vp+4);
            for (int l = wave; l < L_; l += 8){
                int4 raw = *(const int4*)(p.wa_b + (((size_t)(blk*L_ + l))<<9) + lane*8);
                const unsigned* u = (const unsigned*)&raw;
                float s;
                s  = fast_tanh(b2f_lo(u[0]) + hw0.x)*v0.x;
                s += fast_tanh(b2f_hi(u[0]) + hw0.y)*v0.y;
                s += fast_tanh(b2f_lo(u[1]) + hw0.z)*v0.z;
                s += fast_tanh(b2f_hi(u[1]) + hw0.w)*v0.w;
                s += fast_tanh(b2f_lo(u[2]) + hw1.x)*v1.x;
                s += fast_tanh(b2f_hi(u[2]) + hw1.y)*v1.y;
                s += fast_tanh(b2f_lo(u[3]) + hw1.z)*v1.z;
                s += fast_tanh(b2f_hi(u[3]) + hw1.w)*v1.w;
                #pragma unroll
                for (int off=32; off; off>>=1) s += __shfl_down(s, off);
                if (lane==0) e_s[l] = s;
            }
            __syncthreads();
            float ev = (tid < L_) ? e_s[tid] : -3.0e38f;
            red_s[tid] = ev; __syncthreads();
            #pragma unroll
            for (int s=256; s; s>>=1){ if (tid<s) red_s[tid] = fmaxf(red_s[tid], red_s[tid+s]); __syncthreads(); }
            float m = red_s[0]; __syncthreads();
            float pr = (tid < L_) ? __expf(ev - m) : 0.f;
            red_s[tid] = pr; __syncthreads();
            #pragma unroll
            for (int s=256; s; s>>=1){ if (tid<s) red_s[tid] += red_s[tid+s]; __syncthreads(); }
            float inv = 1.f / red_s[0];
            __syncthreads();
            if (tid < L_){
                float al = pr*inv;
                al_s[tid] = al;
                __builtin_nontemporal_store(al, p.alphas + (size_t)blk*TM1*L_ + (size_t)t*L_ + tid);
            }
            // beta = sigmoid(h . beta_W + beta_b)
            float dv = b2f(p.xcat[(size_t)blk*KCAT + D_ + tid]) * p.beta_W[tid];
            red_s[tid] = dv; __syncthreads();
            #pragma unroll
            for (int s=256; s; s>>=1){ if (tid<s) red_s[tid] += red_s[tid+s]; __syncthreads(); }
            float beta = sigmoidf_(red_s[0] + p.beta_b[0]);
            __syncthreads();
            // ctx: d = tid
            const ushort_t* pa = p.a_b + (size_t)blk*L_*D_ + tid;
            float s0 = 0.f;
            #pragma unroll 4
            for (int l=0; l<L_; ++l) s0 = fmaf(al_s[l], b2f(pa[(size_t)l*D_]), s0);
            p.xcat[(size_t)blk*KCAT + tid] = f2b(beta*s0);
        }
        tgt += NBLK; grid_sync(p.bar, tgt);
        // ================= phase B: gates partials (split-K MFMA) =================
        {
            ushort_t* As = (ushort_t*)smem;        // [128][32]
            ushort_t* Bs = As + 128*32;            // [64][32]
            const int bn = (blk & 31) * 64;
            const int ks = blk >> 5;               // 0..3
            const int wm = (wave & 3) * 32;
            const int wnl = (wave >> 2) * 32;
            const int lrow = lane & 15, lk8 = (lane >> 4)*8;
            f32x4 acc[2][2];
            #pragma unroll
            for (int i=0;i<2;i++)
                #pragma unroll
                for (int j=0;j<2;j++) acc[i][j] = (f32x4){0.f,0.f,0.f,0.f};
            const int ra = tid >> 2, kqa = (tid & 3)*8;
            for (int kk = 0; kk < 8; ++kk){
                int k0 = ks*256 + kk*32;
                int4 av = *(const int4*)(p.xcat + (size_t)ra*KCAT + k0 + kqa);
                int4 bv;
                if (tid < 256) bv = *(const int4*)(p.WcatT + (size_t)(bn + ra)*KCAT + k0 + kqa);
                __syncthreads();
                *(int4*)&As[ra*32 + kqa] = av;
                if (tid < 256) *(int4*)&Bs[ra*32 + kqa] = bv;
                __syncthreads();
                bf16x8 af[2], bfr[2];
                #pragma unroll
                for (int i=0;i<2;i++) af[i]  = *(bf16x8*)&As[(wm + i*16 + lrow)*32 + lk8];
                #pragma unroll
                for (int j=0;j<2;j++) bfr[j] = *(bf16x8*)&Bs[(wnl + j*16 + lrow)*32 + lk8];
                #pragma unroll
                for (int i=0;i<2;i++)
                    #pragma unroll
                    for (int j=0;j<2;j++)
                        acc[i][j] = __builtin_amdgcn_mfma_f32_16x16x32_bf16(af[i], bfr[j], acc[i][j], 0, 0, 0);
            }
            const int rq = (lane >> 4) * 4;
            #pragma unroll
            for (int i=0;i<2;i++){
                #pragma unroll
                for (int j=0;j<2;j++){
                    int gcol = bn + wnl + j*16 + lrow;
                    #pragma unroll
                    for (int q=0;q<4;q++){
                        int grow = wm + i*16 + rq + q;
                        p.gp[((size_t)(ks*B_ + grow))*G4H + gcol] = acc[i][j][q];
                    }
                }
            }
        }
        tgt += NBLK; grid_sync(p.bar, tgt);
        // ================= phase C: lstm pointwise + next hW (block-local in b) =================
        {
            const int j = tid;
            const float* eb = p.embWih + ((size_t)(t*B_ + blk))*G4H;
            float gi = eb[j], gf = eb[H_+j], gg = eb[2*H_+j], go = eb[3*H_+j];
            #pragma unroll
            for (int ks=0; ks<4; ks++){
                const float* g = p.gp + ((size_t)(ks*B_ + blk))*G4H;
                gi += g[j]; gf += g[H_+j]; gg += g[2*H_+j]; go += g[3*H_+j];
            }
            float ig = sigmoidf_(gi), fg = sigmoidf_(gf);
            float g2 = fast_tanh(gg), og = sigmoidf_(go);
            float c = fg*p.cbuf[blk*H_+j] + ig*g2;
            float h = og*fast_tanh(c);
            p.cbuf[blk*H_+j] = c;
            ushort_t hb = f2b(h);
            p.xcat[(size_t)blk*KCAT + D_ + j] = hb;
            p.Hall[((size_t)t*B_ + blk)*H_ + j] = hb;
            ushort_t* hls = (ushort_t*)smem;
            hls[j] = hb;
            __syncthreads();
            hw_mfma_lds(hls, p.WhcT, hWl, j);
            __syncthreads();
        }
        // no grid sync needed: next phase A reads only this block's outputs
    }
}

extern "C" void kernel_launch(void* const* d_in, const int* in_sizes, int n_in,
                              void* d_out, int out_size, void* d_ws, size_t ws_size,
                              hipStream_t stream) {
    const float* a      = (const float*)d_in[0];
    const int*   caps   = (const int*)  d_in[1];
    const float* embW   = (const float*)d_in[3];
    const float* Wa     = (const float*)d_in[4];
    const float* Wh     = (const float*)d_in[5];
    const float* Wc     = (const float*)d_in[6];
    const float* v      = (const float*)d_in[7];
    const float* beta_W = (const float*)d_in[8];
    const float* beta_b = (const float*)d_in[9];
    const float* W_ih   = (const float*)d_in[10];
    const float* W_hh   = (const float*)d_in[11];
    const float* b_ih   = (const float*)d_in[12];
    const float* b_hh   = (const float*)d_in[13];
    const float* fc_W   = (const float*)d_in[14];
    const float* fc_b   = (const float*)d_in[15];
    const float* iWh    = (const float*)d_in[16];
    const float* ibh    = (const float*)d_in[17];
    const float* iWc    = (const float*)d_in[18];
    const float* ibc    = (const float*)d_in[19];

    float* out    = (float*)d_out;
    float* alphas = out + (size_t)ROWS*V_;

    // d_out scratch (dead before final logits GEMM overwrites it)
    char* ob = (char*)d_out;
    ushort_t* wa_b   = (ushort_t*)(ob);               // 25,690,112 B
    ushort_t* a_b    = (ushort_t*)(ob + 25690112);    // 25,690,112 B
    float*    embWih = (float*)   (ob + 51380224);    // 19,922,944 B (ends 71.3MB < 97.28MB)

    // d_ws layout (byte offsets)
    char* wb = (char*)d_ws;
    float* mean_ctx = (float*)(wb);              // 262144
    float* cbuf     = (float*)(wb + 262144);     // 262144
    float* h0f      = (float*)(wb + 524288);     // 262144
    unsigned* bar   = (unsigned*)(wb + 1048576); // 4
    float* bias4h   = (float*)(wb + 1179648);    // 8192
    float* gp       = (float*)(wb + 1187840);    // 4194304
    ushort_t* xcat_b = (ushort_t*)(wb + 5382144);   // 262144
    ushort_t* xemb_b = (ushort_t*)(wb + 5644288);   // 1245184
    ushort_t* Hall   = (ushort_t*)(wb + 6889472);   // 2490368
    ushort_t* WaT    = (ushort_t*)(wb + 9379840);   // 524288
    ushort_t* WhcT   = (ushort_t*)(wb + 9904128);   // 524288
    ushort_t* WihT   = (ushort_t*)(wb + 10428416);  // 1048576
    ushort_t* WcatT  = (ushort_t*)(wb + 11476992);  // 4194304
    ushort_t* fcWT   = (ushort_t*)(wb + 15671296);  // 10354688 -> ends ~26MB

    // ---- prep ----
    bias4h_k<<<8, 256, 0, stream>>>(b_ih, b_hh, bias4h, bar);
    transpose_cvt<<<dim3(16,16), 256, 0, stream>>>(Wa, nullptr, A_, D_, A_, WaT, 512, 0);
    transpose_cvt<<<dim3(16,16), 256, 0, stream>>>(Wh, Wc,      A_, H_, A_, WhcT, 512, 0);
    transpose_cvt<<<dim3(64,8),  256, 0, stream>>>(W_ih, nullptr, G4H, E_, G4H, WihT, 256, 0);
    transpose_cvt<<<dim3(64,16), 256, 0, stream>>>(W_ih + (size_t)E_*G4H, nullptr, G4H, D_, G4H, WcatT, KCAT, 0);
    transpose_cvt<<<dim3(64,16), 256, 0, stream>>>(W_hh, nullptr, G4H, H_, G4H, WcatT, KCAT, 512);
    transpose_cvt<<<dim3(316,16),256, 0, stream>>>(fc_W, nullptr, V_, H_, V_, fcWT, 512, 0);
    mean_cvt_k<<<256, 256, 0, stream>>>(a, a_b, mean_ctx);
    gather_emb<<<ROWS, 64, 0, stream>>>(caps, embW, xemb_b);

    gemm64t<<<dim3(8,2), 256, 0, stream>>>(mean_ctx, D_, iWh, H_, h0f, H_, ibh);
    gemm64t<<<dim3(8,2), 256, 0, stream>>>(mean_ctx, D_, iWc, H_, cbuf, H_, ibc);
    cvt_h0_k<<<256, 256, 0, stream>>>(h0f, xcat_b);

    // wa_b = bf16(a @ Wa)    (25088 x 512 x 512)
    gemm_mfma<1,0,0,0><<<dim3(4,196), 256, 0, stream>>>(a_b, D_, WaT, D_, wa_b, A_, A_, D_, nullptr);
    // embWih = xemb @ W_ih[:E] + (b_ih+b_hh)   (2432 x 2048 x 256)
    gemm_mfma<0,1,0,0><<<dim3(16,19), 256, 0, stream>>>(xemb_b, E_, WihT, E_, embWih, G4H, G4H, E_, bias4h);

    // ---- persistent 19-step loop (cooperative) ----
    LoopArgs la;
    la.wa_b = wa_b; la.a_b = a_b; la.v = v; la.beta_W = beta_W; la.beta_b = beta_b;
    la.WcatT = WcatT; la.WhcT = WhcT; la.embWih = embWih; la.cbuf = cbuf;
    la.xcat = xcat_b; la.Hall = Hall; la.gp = gp; la.alphas = alphas; la.bar = bar;
    void* kargs[] = { &la };
    hipLaunchCooperativeKernel((const void*)loop_k, dim3(NBLK), dim3(512), kargs, 0, stream);

    // logits = Hall @ fc_W + fc_b   (2432 x 10000 x 512), NT stores + XCD swizzle
    gemm_mfma<0,1,1,1><<<dim3(1520), 256, 0, stream>>>(Hall, H_, fcWT, H_, out, V_, V_, H_, fc_b);
}